// Round 23
// baseline (165.577 us; speedup 1.0000x reference)
//
#include <hip/hip_runtime.h>
#include <math.h>

#define B_ 64
#define S_ 256
#define V_ 2048
#define NS 12
#define ZOFF 0.001f
#define EPSF 1e-8f
#define EPS2 1e-16f
#define NCHS 32   // v-chunks in latch phase (64 elems each, 1/thread)

// ws layout (float offsets)
#define WS_NSP2 0
#define WS_D0   64                      // [B]
#define WS_N0   128                     // [B]
#define WS_E    256                     // [B][S]
#define WS_R    (WS_E + B_*S_)          // [B][S]
#define WS_NX2  (WS_R + B_*S_)          // [B][S]
#define WS_H    (WS_NX2 + B_*S_)        // [B][NCHS][S][4] quarter partials

typedef float f32x4 __attribute__((ext_vector_type(4)));

template<int CTRL>
__device__ __forceinline__ float dpp_mov(float x) {
    return __int_as_float(__builtin_amdgcn_update_dpp(
        0, __float_as_int(x), CTRL, 0xf, 0xf, true));
}

// 16-lane row sum via DPP rotate-adds (direction-invariant; proven R3-R22)
__device__ __forceinline__ float row16_sum(float x) {
    x += dpp_mov<0x121>(x);
    x += dpp_mov<0x122>(x);
    x += dpp_mov<0x124>(x);
    x += dpp_mov<0x128>(x);
    return x;
}

__device__ __forceinline__ float wave_sum64_fast(float x) {
    x = row16_sum(x);
    x += __shfl_xor(x, 16);
    x += __shfl_xor(x, 32);
    return x;
}

__device__ __forceinline__ void ntstore4(float* p, f32x4 v) {
    __builtin_nontemporal_store(v, (f32x4*)p);
}

// ---------- Phase A (merged): e/r/nx2 per (b,t) + sp/batch norms ----------
__global__ void __launch_bounds__(256) k_e(const float* __restrict__ x,
                                           const float* __restrict__ le,
                                           const float* __restrict__ sp,
                                           const float* __restrict__ l0,
                                           float* __restrict__ ws) {
    int blk = blockIdx.x;
    int tid = threadIdx.x;
    int wave = tid >> 6, lane = tid & 63;
    __shared__ float red4[4][4];
    if (blk >= B_ * S_) {
        int nb = blk - B_ * S_;
        float a = 0.f, b = 0.f;
        if (nb == 0) {
            for (int i = tid; i < V_; i += 256) { float y = sp[i]; a += y * y; }
        } else {
            const float* lr = l0 + (size_t)(nb - 1) * V_;
            for (int i = tid; i < V_; i += 256) {
                float l = lr[i], s = sp[i];
                a += s * l; b += l * l;
            }
        }
        a = wave_sum64_fast(a); b = wave_sum64_fast(b);
        if (lane == 0) { red4[wave][0] = a; red4[wave][1] = b; }
        __syncthreads();
        if (tid == 0) {
            float s0 = red4[0][0] + red4[1][0] + red4[2][0] + red4[3][0];
            float s1 = red4[0][1] + red4[1][1] + red4[2][1] + red4[3][1];
            if (nb == 0) ws[WS_NSP2] = s0;
            else { ws[WS_D0 + nb - 1] = s0; ws[WS_N0 + nb - 1] = s1; }
        }
        return;
    }
    int bt = blk;
    const float4* xb = (const float4*)(x + (size_t)bt * V_);
    const float4* le4 = (const float4*)le;
    const float4* sp4 = (const float4*)sp;
    float dot = 0.f, nx = 0.f, rr = 0.f, nle = 0.f;
#pragma unroll
    for (int k = 0; k < 2; k++) {
        int i = tid + k * 256;
        float4 xv = xb[i], lv = le4[i], sv = sp4[i];
        dot += xv.x * lv.x + xv.y * lv.y + xv.z * lv.z + xv.w * lv.w;
        nx  += xv.x * xv.x + xv.y * xv.y + xv.z * xv.z + xv.w * xv.w;
        rr  += xv.x * sv.x + xv.y * sv.y + xv.z * sv.z + xv.w * sv.w;
        nle += lv.x * lv.x + lv.y * lv.y + lv.z * lv.z + lv.w * lv.w;
    }
    dot = wave_sum64_fast(dot); nx = wave_sum64_fast(nx);
    rr = wave_sum64_fast(rr);   nle = wave_sum64_fast(nle);
    if (lane == 0) {
        red4[wave][0] = dot; red4[wave][1] = nx;
        red4[wave][2] = rr;  red4[wave][3] = nle;
    }
    __syncthreads();
    if (tid == 0) {
        float d  = red4[0][0] + red4[1][0] + red4[2][0] + red4[3][0];
        float n  = red4[0][1] + red4[1][1] + red4[2][1] + red4[3][1];
        float r  = red4[0][2] + red4[1][2] + red4[2][2] + red4[3][2];
        float nl = red4[0][3] + red4[1][3] + red4[2][3] + red4[3][3];
        ws[WS_E + bt]   = d * __frsqrt_rn(fmaxf(nl, EPS2)) * __frsqrt_rn(fmaxf(n, EPS2));
        ws[WS_R + bt]   = r;
        ws[WS_NX2 + bt] = n;
    }
}

// ---------- Phase B: latch scan, 1 v/thread (8 waves/CU); DPP-only h partials ----------
__global__ void __launch_bounds__(64) k_latch(const float* __restrict__ x,
                        const float* __restrict__ latch_init,
                        float* __restrict__ latch_out,
                        float* __restrict__ ws) {
    int c = blockIdx.x, b = blockIdx.y;
    int lane = threadIdx.x;
    int v = c * 64 + lane;

    __shared__ float se[S_];
    for (int t = lane; t < S_; t += 64) se[t] = ws[WS_E + b * S_ + t];
    __syncthreads();

    float latch = latch_init[(size_t)b * V_ + v];
    const float* xb = x + (size_t)b * S_ * V_ + v;
    float* lo = latch_out + (size_t)b * S_ * V_ + v;
    float* hpp = ws + WS_H + (size_t)(b * NCHS + c) * S_ * 4;
    bool hwr = (lane & 15) == 0;
    int hq = lane >> 4;

    auto step = [&](int t, float xv, float e) {
        float rs = row16_sum(latch * xv);
        if (hwr) hpp[t * 4 + hq] = rs;
        latch = fmaf(e, xv - latch, latch);
        __builtin_nontemporal_store(latch, lo + (size_t)t * V_);
    };

    float xc[8]; float ec[8];
#pragma unroll
    for (int k = 0; k < 8; k++) { xc[k] = xb[(size_t)k * V_]; ec[k] = se[k]; }
    for (int t = 0; t < S_; t += 8) {
        float y[8], f[8];
        if (t + 8 < S_) {
#pragma unroll
            for (int k = 0; k < 8; k++) {
                y[k] = xb[(size_t)(t + 8 + k) * V_];
                f[k] = se[t + 8 + k];
            }
        } else {
#pragma unroll
            for (int k = 0; k < 8; k++) { y[k] = 0.f; f[k] = 0.f; }
        }
#pragma unroll
        for (int k = 0; k < 8; k++) step(t + k, xc[k], ec[k]);
#pragma unroll
        for (int k = 0; k < 8; k++) { xc[k] = y[k]; ec[k] = f[k]; }
    }
}

// ---------- Phase C+D fused, wave-specialized producer/consumer ----------
// Wave 0 produces 32-step coef chunks (serial chain, R14-proven math) into
// a double-buffered LDS ring; waves 1-2 consume them with pure 4v scans.
// Consumer prefetch deepened to 16 steps: first-use s_waitcnt comes ~5k cy
// after issue, giving older NT stores (in-order vmcnt retirement) a full
// drain window.
template<bool UP>
__device__ __forceinline__ void chain_chunk(
    int lane, float kq, float inv_nsp,
    float& p, float& d, float& n,
    const float* __restrict__ sh, const float* __restrict__ se_,
    const float* __restrict__ sr_, const float* __restrict__ snx_,
    float* __restrict__ buf, int t0,
    float* __restrict__ pops_b, bool wrpops)
{
    bool act = lane < NS, is0 = (lane == 0), is11 = (lane == 11);
#pragma unroll 4
    for (int k = 0; k < 32; ++k) {
        int t = t0 + k;
        float e = se_[t], r = sr_[t], hh = sh[t], xx = snx_[t];
        float cs = d * inv_nsp * __frsqrt_rn(fmaxf(n, EPS2));
        float pop = cs > 0.f ? cs : __expf(cs) - 1.f;
        float push = 1.f - pop;
        float ez = act ? exp2f(p * kq) : 0.f;
        float s = row16_sum(ez);
        float psh = ez * __frcp_rn(s);
        float fm = UP ? dpp_mov<0x12F>(psh) : dpp_mov<0x121>(psh);  // from lane-1 (mod16)
        float fp = UP ? dpp_mov<0x121>(psh) : dpp_mov<0x12F>(psh);  // from lane+1 (mod16)
        float wm = UP ? dpp_mov<0x12B>(psh) : dpp_mov<0x125>(psh);  // from lane+11 (mod16)
        float wp = UP ? dpp_mov<0x125>(psh) : dpp_mov<0x12B>(psh);  // from lane+5  (mod16)
        float push_p = is0  ? wm : fm;   // psh[(n-1) mod 12]
        float pop_p  = is11 ? wp : fp;   // psh[(n+1) mod 12]
        float bb = push * push_p;
        float cc = pop * psh;
        float a  = 1.f - bb - cc;
        float pnew = fmaf(pop, pop_p, bb);
        float4 cv = act ? make_float4(a, bb, cc * ZOFF, pnew)
                        : make_float4(pop, 0.f, 0.f, 0.f);
        if (lane <= NS) *(float4*)(buf + k * 52 + lane * 4) = cv;
        if (wrpops && lane == 0) pops_b[t] = pop;
        p = pnew;
        float om = 1.f - e;
        d = fmaf(om, d, e * r);
        n = fmaf(om * om, n, fmaf(2.f * e * om, hh, e * e * xx));
    }
}

__global__ void __launch_bounds__(192) k_stackptr(const float* __restrict__ sharpen_ptr,
                                                  const float* __restrict__ x,
                                                  float* __restrict__ ws,
                                                  float* __restrict__ pops_out,
                                                  float* __restrict__ outputs,
                                                  float* __restrict__ tops) {
    int b = blockIdx.y, ch = blockIdx.x;   // ch in [0,4)
    int tid = threadIdx.x;
    int w = tid / 64, lane = tid % 64;
    __shared__ float sh[S_], se_[S_], sr_[S_], snx_[S_];
    __shared__ float scoef[2][32][52];   // double-buffered 32-step chunks

    // prologue: fold h partials + stage chain inputs (parallel, 192 threads)
    const float4* hp4 = (const float4*)(ws + WS_H) + (size_t)b * NCHS * S_;
    for (int t = tid; t < S_; t += 192) {
        float h = 0.f;
#pragma unroll
        for (int c = 0; c < NCHS; c++) {
            float4 vv = hp4[(size_t)c * S_ + t];
            h += (vv.x + vv.y) + (vv.z + vv.w);
        }
        sh[t] = h;
        se_[t]  = ws[WS_E + b * S_ + t];
        sr_[t]  = ws[WS_R + b * S_ + t];
        snx_[t] = ws[WS_NX2 + b * S_ + t];
    }
    __syncthreads();

    float kq = sharpen_ptr[0] * 1.44269504f;
    float inv_nsp = 1.f / fmaxf(sqrtf(ws[WS_NSP2]), EPSF);

    if (w == 0) {
        // ---- producer wave: serial chain, chunk-at-a-time ----
        float d = ws[WS_D0 + b];
        float n = ws[WS_N0 + b];
        float p = (lane == 0) ? 1.f : 0.f;
        float* pops_b = pops_out + (size_t)b * S_;
        bool wrpops = (ch == 0);
        float pw = dpp_mov<0x121>((float)lane);
        bool up = (__builtin_amdgcn_readlane(__float_as_int(pw), 0) == __float_as_int(1.0f));
        for (int c = 0; c <= 8; ++c) {
            if (c < 8) {
                if (up) chain_chunk<true>(lane, kq, inv_nsp, p, d, n, sh, se_, sr_, snx_,
                                          &scoef[c & 1][0][0], c * 32, pops_b, wrpops);
                else    chain_chunk<false>(lane, kq, inv_nsp, p, d, n, sh, se_, sr_, snx_,
                                           &scoef[c & 1][0][0], c * 32, pops_b, wrpops);
            }
            __syncthreads();
        }
    } else {
        // ---- consumer waves: pure scan, 4 v/thread, 16-step prefetch ----
        int v = ch * 512 + (w - 1) * 256 + lane * 4;
        const float* xp = x + (size_t)b * S_ * V_ + v;
        float* op = outputs + (size_t)b * S_ * V_ + v;
        float* tp = tops + (size_t)b * S_ * V_ + v;

        f32x4 st[NS];
#pragma unroll
        for (int i = 0; i < NS; i++) st[i] = (f32x4){ZOFF, ZOFF, ZOFF, ZOFF};

        auto scan_step = [&](const float* cf, int t, f32x4 xv) {
            f32x4 top = (f32x4){0.f, 0.f, 0.f, 0.f};
#pragma unroll
            for (int i = 0; i < NS; i++) {
                float4 c4 = *(const float4*)(cf + i * 4);
                f32x4 bx;
                bx.x = fmaf(c4.y, xv.x, c4.z);
                bx.y = fmaf(c4.y, xv.y, c4.z);
                bx.z = fmaf(c4.y, xv.z, c4.z);
                bx.w = fmaf(c4.y, xv.w, c4.z);
                st[i].x = fmaf(c4.x, st[i].x, bx.x);
                st[i].y = fmaf(c4.x, st[i].y, bx.y);
                st[i].z = fmaf(c4.x, st[i].z, bx.z);
                st[i].w = fmaf(c4.x, st[i].w, bx.w);
                top.x = fmaf(c4.w, st[i].x, top.x);
                top.y = fmaf(c4.w, st[i].y, top.y);
                top.z = fmaf(c4.w, st[i].z, top.z);
                top.w = fmaf(c4.w, st[i].w, top.w);
            }
            float pop = cf[48];
            ntstore4(tp + (size_t)t * V_, top);
            f32x4 ot = {pop * top.x, pop * top.y, pop * top.z, pop * top.w};
            ntstore4(op + (size_t)t * V_, ot);
        };

        f32x4 xc[16];
#pragma unroll
        for (int k = 0; k < 16; k++) xc[k] = *(const f32x4*)(xp + (size_t)k * V_);

        __syncthreads();   // matches producer's c=0 barrier (chunk 0 ready)
        for (int c = 1; c <= 8; ++c) {
            int t0 = (c - 1) * 32;
            const float* buf = &scoef[(c - 1) & 1][0][0];
#pragma unroll
            for (int g = 0; g < 2; ++g) {
                int t = t0 + g * 16;
                f32x4 y[16];
                if (t + 16 < S_) {
#pragma unroll
                    for (int k = 0; k < 16; k++)
                        y[k] = *(const f32x4*)(xp + (size_t)(t + 16 + k) * V_);
                } else {
#pragma unroll
                    for (int k = 0; k < 16; k++) y[k] = (f32x4){0.f, 0.f, 0.f, 0.f};
                }
#pragma unroll
                for (int k = 0; k < 16; k++)
                    scan_step(buf + (g * 16 + k) * 52, t + k, xc[k]);
#pragma unroll
                for (int k = 0; k < 16; k++) xc[k] = y[k];
            }
            __syncthreads();
        }
    }
}

extern "C" void kernel_launch(void* const* d_in, const int* in_sizes, int n_in,
                              void* d_out, int out_size, void* d_ws, size_t ws_size,
                              hipStream_t stream) {
    const float* x           = (const float*)d_in[0];
    const float* latch_init  = (const float*)d_in[1];
    const float* should_pop  = (const float*)d_in[2];
    const float* sharpen_ptr = (const float*)d_in[3];
    const float* latch_en    = (const float*)d_in[4];

    float* out = (float*)d_out;
    const size_t BSV = (size_t)B_ * S_ * V_;
    float* outputs      = out;
    float* latch_states = out + BSV;
    float* pops         = out + 2 * BSV;
    float* tops         = out + 2 * BSV + (size_t)B_ * S_;
    float* ws = (float*)d_ws;

    k_e<<<B_ * S_ + 1 + B_, 256, 0, stream>>>(x, latch_en, should_pop, latch_init, ws);
    k_latch<<<dim3(NCHS, B_), 64, 0, stream>>>(x, latch_init, latch_states, ws);
    k_stackptr<<<dim3(4, B_), 192, 0, stream>>>(sharpen_ptr, x, ws, pops, outputs, tops);
}

// Round 24
// 162.751 us; speedup vs baseline: 1.0174x; 1.0174x over previous
//
#include <hip/hip_runtime.h>
#include <math.h>

#define B_ 64
#define S_ 256
#define V_ 2048
#define NS 12
#define ZOFF 0.001f
#define EPSF 1e-8f
#define EPS2 1e-16f
#define NCHS 32   // v-chunks in latch phase (64 elems each, 1/thread)

// ws layout (float offsets)
#define WS_NSP2 0
#define WS_D0   64                      // [B]
#define WS_N0   128                     // [B]
#define WS_E    256                     // [B][S]
#define WS_R    (WS_E + B_*S_)          // [B][S]
#define WS_NX2  (WS_R + B_*S_)          // [B][S]
#define WS_H    (WS_NX2 + B_*S_)        // [B][NCHS][S][4] quarter partials

typedef float f32x4 __attribute__((ext_vector_type(4)));

template<int CTRL>
__device__ __forceinline__ float dpp_mov(float x) {
    return __int_as_float(__builtin_amdgcn_update_dpp(
        0, __float_as_int(x), CTRL, 0xf, 0xf, true));
}

// 16-lane row sum via DPP rotate-adds (direction-invariant; proven R3-R23)
__device__ __forceinline__ float row16_sum(float x) {
    x += dpp_mov<0x121>(x);
    x += dpp_mov<0x122>(x);
    x += dpp_mov<0x124>(x);
    x += dpp_mov<0x128>(x);
    return x;
}

__device__ __forceinline__ float wave_sum64_fast(float x) {
    x = row16_sum(x);
    x += __shfl_xor(x, 16);
    x += __shfl_xor(x, 32);
    return x;
}

__device__ __forceinline__ void ntstore4(float* p, f32x4 v) {
    __builtin_nontemporal_store(v, (f32x4*)p);
}

// ---------- Phase A (merged): e/r/nx2 per (b,t) + sp/batch norms ----------
__global__ void __launch_bounds__(256) k_e(const float* __restrict__ x,
                                           const float* __restrict__ le,
                                           const float* __restrict__ sp,
                                           const float* __restrict__ l0,
                                           float* __restrict__ ws) {
    int blk = blockIdx.x;
    int tid = threadIdx.x;
    int wave = tid >> 6, lane = tid & 63;
    __shared__ float red4[4][4];
    if (blk >= B_ * S_) {
        int nb = blk - B_ * S_;
        float a = 0.f, b = 0.f;
        if (nb == 0) {
            for (int i = tid; i < V_; i += 256) { float y = sp[i]; a += y * y; }
        } else {
            const float* lr = l0 + (size_t)(nb - 1) * V_;
            for (int i = tid; i < V_; i += 256) {
                float l = lr[i], s = sp[i];
                a += s * l; b += l * l;
            }
        }
        a = wave_sum64_fast(a); b = wave_sum64_fast(b);
        if (lane == 0) { red4[wave][0] = a; red4[wave][1] = b; }
        __syncthreads();
        if (tid == 0) {
            float s0 = red4[0][0] + red4[1][0] + red4[2][0] + red4[3][0];
            float s1 = red4[0][1] + red4[1][1] + red4[2][1] + red4[3][1];
            if (nb == 0) ws[WS_NSP2] = s0;
            else { ws[WS_D0 + nb - 1] = s0; ws[WS_N0 + nb - 1] = s1; }
        }
        return;
    }
    int bt = blk;
    const float4* xb = (const float4*)(x + (size_t)bt * V_);
    const float4* le4 = (const float4*)le;
    const float4* sp4 = (const float4*)sp;
    float dot = 0.f, nx = 0.f, rr = 0.f, nle = 0.f;
#pragma unroll
    for (int k = 0; k < 2; k++) {
        int i = tid + k * 256;
        float4 xv = xb[i], lv = le4[i], sv = sp4[i];
        dot += xv.x * lv.x + xv.y * lv.y + xv.z * lv.z + xv.w * lv.w;
        nx  += xv.x * xv.x + xv.y * xv.y + xv.z * xv.z + xv.w * xv.w;
        rr  += xv.x * sv.x + xv.y * sv.y + xv.z * sv.z + xv.w * sv.w;
        nle += lv.x * lv.x + lv.y * lv.y + lv.z * lv.z + lv.w * lv.w;
    }
    dot = wave_sum64_fast(dot); nx = wave_sum64_fast(nx);
    rr = wave_sum64_fast(rr);   nle = wave_sum64_fast(nle);
    if (lane == 0) {
        red4[wave][0] = dot; red4[wave][1] = nx;
        red4[wave][2] = rr;  red4[wave][3] = nle;
    }
    __syncthreads();
    if (tid == 0) {
        float d  = red4[0][0] + red4[1][0] + red4[2][0] + red4[3][0];
        float n  = red4[0][1] + red4[1][1] + red4[2][1] + red4[3][1];
        float r  = red4[0][2] + red4[1][2] + red4[2][2] + red4[3][2];
        float nl = red4[0][3] + red4[1][3] + red4[2][3] + red4[3][3];
        ws[WS_E + bt]   = d * __frsqrt_rn(fmaxf(nl, EPS2)) * __frsqrt_rn(fmaxf(n, EPS2));
        ws[WS_R + bt]   = r;
        ws[WS_NX2 + bt] = n;
    }
}

// ---------- Phase B: latch scan, 1 v/thread (8 waves/CU); DPP-only h partials ----------
__global__ void __launch_bounds__(64) k_latch(const float* __restrict__ x,
                        const float* __restrict__ latch_init,
                        float* __restrict__ latch_out,
                        float* __restrict__ ws) {
    int c = blockIdx.x, b = blockIdx.y;
    int lane = threadIdx.x;
    int v = c * 64 + lane;

    __shared__ float se[S_];
    for (int t = lane; t < S_; t += 64) se[t] = ws[WS_E + b * S_ + t];
    __syncthreads();

    float latch = latch_init[(size_t)b * V_ + v];
    const float* xb = x + (size_t)b * S_ * V_ + v;
    float* lo = latch_out + (size_t)b * S_ * V_ + v;
    float* hpp = ws + WS_H + (size_t)(b * NCHS + c) * S_ * 4;
    bool hwr = (lane & 15) == 0;
    int hq = lane >> 4;

    auto step = [&](int t, float xv, float e) {
        float rs = row16_sum(latch * xv);
        if (hwr) hpp[t * 4 + hq] = rs;
        latch = fmaf(e, xv - latch, latch);
        __builtin_nontemporal_store(latch, lo + (size_t)t * V_);
    };

    float xc[8]; float ec[8];
#pragma unroll
    for (int k = 0; k < 8; k++) { xc[k] = xb[(size_t)k * V_]; ec[k] = se[k]; }
    for (int t = 0; t < S_; t += 8) {
        float y[8], f[8];
        if (t + 8 < S_) {
#pragma unroll
            for (int k = 0; k < 8; k++) {
                y[k] = xb[(size_t)(t + 8 + k) * V_];
                f[k] = se[t + 8 + k];
            }
        } else {
#pragma unroll
            for (int k = 0; k < 8; k++) { y[k] = 0.f; f[k] = 0.f; }
        }
#pragma unroll
        for (int k = 0; k < 8; k++) step(t + k, xc[k], ec[k]);
#pragma unroll
        for (int k = 0; k < 8; k++) { xc[k] = y[k]; ec[k] = f[k]; }
    }
}

// ---------- Phase C+D fused, wave-specialized producer/consumer ----------
// Wave 0 produces 32-step coef chunks (serial chain, R14-proven math) into
// a double-buffered LDS ring; waves 1-2 consume them with pure 4v scans.
// Iteration c: producer fills buf[c&1], consumers drain buf[(c-1)&1] --
// disjoint buffers, barrier-separated. 9 chunk barriers total.
template<bool UP>
__device__ __forceinline__ void chain_chunk(
    int lane, float kq, float inv_nsp,
    float& p, float& d, float& n,
    const float* __restrict__ sh, const float* __restrict__ se_,
    const float* __restrict__ sr_, const float* __restrict__ snx_,
    float* __restrict__ buf, int t0,
    float* __restrict__ pops_b, bool wrpops)
{
    bool act = lane < NS, is0 = (lane == 0), is11 = (lane == 11);
#pragma unroll 4
    for (int k = 0; k < 32; ++k) {
        int t = t0 + k;
        float e = se_[t], r = sr_[t], hh = sh[t], xx = snx_[t];
        float cs = d * inv_nsp * __frsqrt_rn(fmaxf(n, EPS2));
        float pop = cs > 0.f ? cs : __expf(cs) - 1.f;
        float push = 1.f - pop;
        float ez = act ? exp2f(p * kq) : 0.f;
        float s = row16_sum(ez);
        float psh = ez * __frcp_rn(s);
        float fm = UP ? dpp_mov<0x12F>(psh) : dpp_mov<0x121>(psh);  // from lane-1 (mod16)
        float fp = UP ? dpp_mov<0x121>(psh) : dpp_mov<0x12F>(psh);  // from lane+1 (mod16)
        float wm = UP ? dpp_mov<0x12B>(psh) : dpp_mov<0x125>(psh);  // from lane+11 (mod16)
        float wp = UP ? dpp_mov<0x125>(psh) : dpp_mov<0x12B>(psh);  // from lane+5  (mod16)
        float push_p = is0  ? wm : fm;   // psh[(n-1) mod 12]
        float pop_p  = is11 ? wp : fp;   // psh[(n+1) mod 12]
        float bb = push * push_p;
        float cc = pop * psh;
        float a  = 1.f - bb - cc;
        float pnew = fmaf(pop, pop_p, bb);
        float4 cv = act ? make_float4(a, bb, cc * ZOFF, pnew)
                        : make_float4(pop, 0.f, 0.f, 0.f);
        if (lane <= NS) *(float4*)(buf + k * 52 + lane * 4) = cv;
        if (wrpops && lane == 0) pops_b[t] = pop;
        p = pnew;
        float om = 1.f - e;
        d = fmaf(om, d, e * r);
        n = fmaf(om * om, n, fmaf(2.f * e * om, hh, e * e * xx));
    }
}

__global__ void __launch_bounds__(192) k_stackptr(const float* __restrict__ sharpen_ptr,
                                                  const float* __restrict__ x,
                                                  float* __restrict__ ws,
                                                  float* __restrict__ pops_out,
                                                  float* __restrict__ outputs,
                                                  float* __restrict__ tops) {
    int b = blockIdx.y, ch = blockIdx.x;   // ch in [0,4)
    int tid = threadIdx.x;
    int w = tid / 64, lane = tid % 64;
    __shared__ float sh[S_], se_[S_], sr_[S_], snx_[S_];
    __shared__ float scoef[2][32][52];   // double-buffered 32-step chunks

    // prologue: fold h partials + stage chain inputs (parallel, 192 threads)
    const float4* hp4 = (const float4*)(ws + WS_H) + (size_t)b * NCHS * S_;
    for (int t = tid; t < S_; t += 192) {
        float h = 0.f;
#pragma unroll
        for (int c = 0; c < NCHS; c++) {
            float4 vv = hp4[(size_t)c * S_ + t];
            h += (vv.x + vv.y) + (vv.z + vv.w);
        }
        sh[t] = h;
        se_[t]  = ws[WS_E + b * S_ + t];
        sr_[t]  = ws[WS_R + b * S_ + t];
        snx_[t] = ws[WS_NX2 + b * S_ + t];
    }
    __syncthreads();

    float kq = sharpen_ptr[0] * 1.44269504f;
    float inv_nsp = 1.f / fmaxf(sqrtf(ws[WS_NSP2]), EPSF);

    if (w == 0) {
        // ---- producer wave: serial chain, chunk-at-a-time ----
        float d = ws[WS_D0 + b];
        float n = ws[WS_N0 + b];
        float p = (lane == 0) ? 1.f : 0.f;
        float* pops_b = pops_out + (size_t)b * S_;
        bool wrpops = (ch == 0);
        // one-time DPP direction probe (hardware-fixed, wave-uniform; proven R9)
        float pw = dpp_mov<0x121>((float)lane);
        bool up = (__builtin_amdgcn_readlane(__float_as_int(pw), 0) == __float_as_int(1.0f));
        for (int c = 0; c <= 8; ++c) {
            if (c < 8) {
                if (up) chain_chunk<true>(lane, kq, inv_nsp, p, d, n, sh, se_, sr_, snx_,
                                          &scoef[c & 1][0][0], c * 32, pops_b, wrpops);
                else    chain_chunk<false>(lane, kq, inv_nsp, p, d, n, sh, se_, sr_, snx_,
                                           &scoef[c & 1][0][0], c * 32, pops_b, wrpops);
            }
            __syncthreads();
        }
    } else {
        // ---- consumer waves: pure scan, 4 v/thread ----
        int v = ch * 512 + (w - 1) * 256 + lane * 4;
        const float* xp = x + (size_t)b * S_ * V_ + v;
        float* op = outputs + (size_t)b * S_ * V_ + v;
        float* tp = tops + (size_t)b * S_ * V_ + v;

        f32x4 st[NS];
#pragma unroll
        for (int i = 0; i < NS; i++) st[i] = (f32x4){ZOFF, ZOFF, ZOFF, ZOFF};

        auto scan_step = [&](const float* cf, int t, f32x4 xv) {
            f32x4 top = (f32x4){0.f, 0.f, 0.f, 0.f};
#pragma unroll
            for (int i = 0; i < NS; i++) {
                float4 c4 = *(const float4*)(cf + i * 4);
                f32x4 bx;
                bx.x = fmaf(c4.y, xv.x, c4.z);
                bx.y = fmaf(c4.y, xv.y, c4.z);
                bx.z = fmaf(c4.y, xv.z, c4.z);
                bx.w = fmaf(c4.y, xv.w, c4.z);
                st[i].x = fmaf(c4.x, st[i].x, bx.x);
                st[i].y = fmaf(c4.x, st[i].y, bx.y);
                st[i].z = fmaf(c4.x, st[i].z, bx.z);
                st[i].w = fmaf(c4.x, st[i].w, bx.w);
                top.x = fmaf(c4.w, st[i].x, top.x);
                top.y = fmaf(c4.w, st[i].y, top.y);
                top.z = fmaf(c4.w, st[i].z, top.z);
                top.w = fmaf(c4.w, st[i].w, top.w);
            }
            float pop = cf[48];
            ntstore4(tp + (size_t)t * V_, top);
            f32x4 ot = {pop * top.x, pop * top.y, pop * top.z, pop * top.w};
            ntstore4(op + (size_t)t * V_, ot);
        };

        f32x4 xc[8];
#pragma unroll
        for (int k = 0; k < 8; k++) xc[k] = *(const f32x4*)(xp + (size_t)k * V_);

        __syncthreads();   // matches producer's c=0 barrier (chunk 0 ready)
        for (int c = 1; c <= 8; ++c) {
            int t0 = (c - 1) * 32;
            const float* buf = &scoef[(c - 1) & 1][0][0];
#pragma unroll
            for (int g = 0; g < 4; ++g) {
                int t = t0 + g * 8;
                f32x4 y[8];
                if (t + 8 < S_) {
#pragma unroll
                    for (int k = 0; k < 8; k++)
                        y[k] = *(const f32x4*)(xp + (size_t)(t + 8 + k) * V_);
                } else {
#pragma unroll
                    for (int k = 0; k < 8; k++) y[k] = (f32x4){0.f, 0.f, 0.f, 0.f};
                }
#pragma unroll
                for (int k = 0; k < 8; k++)
                    scan_step(buf + (g * 8 + k) * 52, t + k, xc[k]);
#pragma unroll
                for (int k = 0; k < 8; k++) xc[k] = y[k];
            }
            __syncthreads();
        }
    }
}

extern "C" void kernel_launch(void* const* d_in, const int* in_sizes, int n_in,
                              void* d_out, int out_size, void* d_ws, size_t ws_size,
                              hipStream_t stream) {
    const float* x           = (const float*)d_in[0];
    const float* latch_init  = (const float*)d_in[1];
    const float* should_pop  = (const float*)d_in[2];
    const float* sharpen_ptr = (const float*)d_in[3];
    const float* latch_en    = (const float*)d_in[4];

    float* out = (float*)d_out;
    const size_t BSV = (size_t)B_ * S_ * V_;
    float* outputs      = out;
    float* latch_states = out + BSV;
    float* pops         = out + 2 * BSV;
    float* tops         = out + 2 * BSV + (size_t)B_ * S_;
    float* ws = (float*)d_ws;

    k_e<<<B_ * S_ + 1 + B_, 256, 0, stream>>>(x, latch_en, should_pop, latch_init, ws);
    k_latch<<<dim3(NCHS, B_), 64, 0, stream>>>(x, latch_init, latch_states, ws);
    k_stackptr<<<dim3(4, B_), 192, 0, stream>>>(sharpen_ptr, x, ws, pops, outputs, tops);
}